// Round 8
// baseline (1446.211 us; speedup 1.0000x reference)
//
#include <hip/hip_runtime.h>
#include <math.h>
#include <stdint.h>

typedef _Float16 f16;
typedef _Float16 f16x8 __attribute__((ext_vector_type(8)));
typedef float    f32x16 __attribute__((ext_vector_type(16)));

#define NBLK 256
#define NTHR 512
#define MROW 64

// ---- d_ws fragment layout (identical to r6/r7, validated) ----
#define FC1_F 512
#define FC2_F 640
#define ENC_F 656
#define TOT_F 1232
#define TOT_E (TOT_F*512)

#define MFMA32(a,b,c) __builtin_amdgcn_mfma_f32_32x32x16_f16((a),(b),(c),0,0,0)
#define VMW(n)  asm volatile("s_waitcnt vmcnt(" #n ")" ::: "memory")
#define LGKM0() asm volatile("s_waitcnt lgkmcnt(0)" ::: "memory")

// DMA one 1KB B-fragment: lane l supplies global addr (base + l*16B); LDS dest is
// wave-uniform base, HW adds lane*16. Dest layout == exactly the old register layout.
__device__ __forceinline__ void gld16(const f16* g, f16* lds){
  __builtin_amdgcn_global_load_lds(
      (const __attribute__((address_space(1))) void*)(uintptr_t)(const void*)g,
      (__attribute__((address_space(3))) void*)(uint32_t)(uintptr_t)(void*)lds,
      16, 0, 0);
}

__device__ __forceinline__ float sigm(float v){
  return __fdividef(1.0f, 1.0f + __expf(-v));
}
__device__ __forceinline__ float tanh_f(float v){
  float t = fminf(v, 8.0f);
  float e = __expf(2.0f * t);
  return 1.0f - 2.0f * __fdividef(1.0f, e + 1.0f);
}
__device__ __forceinline__ int eH(int row, int k){ return row*256 + (k ^ ((row & 7) << 3)); }
__device__ __forceinline__ int eX(int row, int k){ return row*128 + (k ^ ((row & 7) << 3)); }

// ---------------- prep: pack weights as fp16 32x32x16 B-fragments (byte-identical to r6/r7) ----------------
__global__ void prep_pack(const float* __restrict__ eWih, const float* __restrict__ eWhh,
                          const float* __restrict__ dWih, const float* __restrict__ dWhh,
                          const float* __restrict__ f1W,  const float* __restrict__ f2W,
                          f16* __restrict__ ws16)
{
  int idx = blockIdx.x * 256 + threadIdx.x;
  if (idx >= TOT_E) return;
  int frag = idx >> 9;
  int lo   = idx & 511;
  int l    = lo >> 3;
  int jj   = lo & 7;
  int c32  = l & 31;
  int half = l >> 5;
  int kin  = half*8 + jj;
  float v = 0.0f;
  if (frag < FC1_F){
    int ct = frag >> 6, st = (frag >> 4) & 3, ks = frag & 15;
    int col = ct*32 + c32, k = ks*16 + kin;
    if      (st == 0) v = dWih[col*256 + k]        + dWhh[col*256 + k];
    else if (st == 1) v = dWih[(256+col)*256 + k]  + dWhh[(256+col)*256 + k];
    else if (st == 2) v = dWih[(512+col)*256 + k];
    else              v = dWhh[(512+col)*256 + k];
  } else if (frag < FC2_F){
    int f = frag - FC1_F, ct = f >> 4, ks = f & 15;
    int col = ct*32 + c32, k = ks*16 + kin;
    v = f1W[col*256 + k];
  } else if (frag < ENC_F){
    int ks = frag - FC2_F, k = ks*16 + kin;
    v = (c32 < 2) ? f2W[c32*256 + k] : 0.0f;
  } else {
    int f = frag - ENC_F, ct = f / 72, r = f % 72;
    int col = ct*32 + c32;
    if (r < 24){ int st = r >> 3, ks = r & 7;  v = eWih[(st*256 + col)*128 + ks*16 + kin]; }
    else { r -= 24; int st = r >> 4, ks = r & 15; v = eWhh[(st*256 + col)*256 + ks*16 + kin]; }
  }
  ws16[idx] = (f16)v;
}

// ---------------- fused persistent kernel ----------------
__global__ __launch_bounds__(NTHR, 1)
void fused_net(const float* __restrict__ x,
               const float* __restrict__ emW, const float* __restrict__ emb_,
               const float* __restrict__ evW, const float* __restrict__ evb,
               const float* __restrict__ ebih, const float* __restrict__ ebhh,
               const float* __restrict__ dbih, const float* __restrict__ dbhh,
               const float* __restrict__ f1b, const float* __restrict__ f2b,
               const f16* __restrict__ ws16, float* __restrict__ out)
{
  __shared__ __align__(16) f16 hA[16384];   // [64][256] h ping
  __shared__ __align__(16) f16 hB[16384];   // [64][256] h pong / fc1-out
  __shared__ __align__(16) f16 stg[32768];  // B-stage: 2 slots x 8 waves x 2048 (4 frags)
  __shared__ __align__(16) f16 wfx[8192];   // encoder: xb [64][128]; decoder: 16 FC2 frags

  const int tid  = threadIdx.x;
  const int r0   = blockIdx.x * MROW;
  const int l    = tid & 63;
  const int w    = tid >> 6;
  const int c32  = l & 31;
  const int half = l >> 5;

  f16* hp = hA;
  f16* hq = hB;

  const int abase = c32*256 + ((half*8) ^ ((l & 7) << 3));
  const int xbase = c32*128 + ((half*8) ^ ((l & 7) << 3));
  const int colm  = w*32 + c32;

  f16* sb0 = stg + (size_t)w*2048;          // wave-private slot 0 (uniform per wave)
  f16* sb1 = stg + (size_t)(8 + w)*2048;    // wave-private slot 1

  // per-lane global bases into packed weights
  const f16* wdecL = ws16 + (size_t)(w*64)*512           + (size_t)l*8;
  const f16* wfc1L = ws16 + (size_t)(FC1_F + w*16)*512   + (size_t)l*8;
  const f16* wfc2L = ws16 + (size_t)FC2_F*512            + (size_t)l*8;
  const f16* wencL = ws16 + (size_t)(ENC_F + w*72)*512   + (size_t)l*8;

  for (int i = tid; i < 16384; i += NTHR) hA[i] = (f16)0.0f;   // h0 = 0
  __syncthreads();

  // =============== ENCODER: 9 GRU steps ===============
  {
    const float ebr = ebih[colm]       + ebhh[colm];
    const float ebz = ebih[256 + colm] + ebhh[256 + colm];
    const float ebn = ebih[512 + colm];
    const float ebh = ebhh[512 + colm];

    #pragma unroll 1
    for (int t = 0; t < 9; ++t){
      // stage units 0,1 (x-part frags st*8+u); embed phase + barrier cover latency
      #pragma unroll
      for (int st = 0; st < 3; ++st) gld16(wencL + (size_t)(st*8 + 0)*512, sb0 + st*512);
      #pragma unroll
      for (int st = 0; st < 3; ++st) gld16(wencL + (size_t)(st*8 + 1)*512, sb1 + st*512);

      { // xt = tanh(embedding) -> wfx (as xb)
        int e  = tid & 127;
        int rq = tid >> 7;
        const float* Wp = (t < 8) ? (evW + e*6) : (emW + e*6);
        float bb = (t < 8) ? evb[e] : emb_[e];
        float w0 = Wp[0], w1 = Wp[1], w2 = Wp[2], w3 = Wp[3], w4 = Wp[4], w5 = Wp[5];
        int xo = (t < 8) ? (6 + t*6) : 0;
        #pragma unroll 1
        for (int rr = 0; rr < 16; ++rr){
          int row = rq*16 + rr;
          const float* xs = x + (size_t)(r0 + row)*54 + xo;
          float a = bb + xs[0]*w0 + xs[1]*w1 + xs[2]*w2 + xs[3]*w3 + xs[4]*w4 + xs[5]*w5;
          wfx[eX(row, e)] = (f16)tanh_f(a);
        }
      }
      __syncthreads();   // drains vmcnt -> units 0,1 resident

      f32x16 aR[2], aZ[2], aN[2], aH[2];
      #pragma unroll
      for (int rt = 0; rt < 2; ++rt){ aR[rt] = 0.f; aZ[rt] = 0.f; aN[rt] = 0.f; aH[rt] = 0.f; }

      // 24 units: u<8 = x-part (A from wfx, streams r,z,n), u>=8 = h-part (A from hp, r,z,h)
      #pragma unroll
      for (int u = 0; u < 24; ++u){
        f16* sb = (u & 1) ? sb1 : sb0;
        f16x8 b0 = *(const f16x8*)(sb + 0*512 + l*8);
        f16x8 b1 = *(const f16x8*)(sb + 1*512 + l*8);
        f16x8 b2 = *(const f16x8*)(sb + 2*512 + l*8);
        if (u < 8){
          f16x8 a0 = *(const f16x8*)(wfx + ((xbase       ) ^ (u*16)));
          f16x8 a1 = *(const f16x8*)(wfx + ((xbase + 4096) ^ (u*16)));
          aR[0] = MFMA32(a0, b0, aR[0]);  aR[1] = MFMA32(a1, b0, aR[1]);
          aZ[0] = MFMA32(a0, b1, aZ[0]);  aZ[1] = MFMA32(a1, b1, aZ[1]);
          aN[0] = MFMA32(a0, b2, aN[0]);  aN[1] = MFMA32(a1, b2, aN[1]);
        } else {
          int ks = u - 8;
          f16x8 a0 = *(const f16x8*)(hp + ((abase       ) ^ (ks*16)));
          f16x8 a1 = *(const f16x8*)(hp + ((abase + 8192) ^ (ks*16)));
          aR[0] = MFMA32(a0, b0, aR[0]);  aR[1] = MFMA32(a1, b0, aR[1]);
          aZ[0] = MFMA32(a0, b1, aZ[0]);  aZ[1] = MFMA32(a1, b1, aZ[1]);
          aH[0] = MFMA32(a0, b2, aH[0]);  aH[1] = MFMA32(a1, b2, aH[1]);
        }
        if (u < 22){
          LGKM0();                              // slot reads done -> safe to overwrite
          const int uu = u + 2;
          #pragma unroll
          for (int st = 0; st < 3; ++st){
            int F = (uu < 8) ? (st*8 + uu) : (24 + st*16 + (uu - 8));
            gld16(wencL + (size_t)F*512, sb + st*512);
          }
          VMW(3);                               // next unit's 3 frags resident
        } else if (u == 22){ VMW(0); }
      }
      // epilogue -> hq
      #pragma unroll
      for (int rt = 0; rt < 2; ++rt){
        #pragma unroll
        for (int rg = 0; rg < 16; ++rg){
          int rr  = (rg & 3) + 8*(rg >> 2) + 4*half;
          int row = rt*32 + rr;
          int el  = row*256 + (colm ^ ((rr & 7) << 3));
          float rv = sigm(aR[rt][rg] + ebr);
          float zv = sigm(aZ[rt][rg] + ebz);
          float nv = tanh_f(aN[rt][rg] + ebn + rv*(aH[rt][rg] + ebh));
          float ho = (float)hp[el];
          hq[el] = (f16)(nv + zv*(ho - nv));
        }
      }
      __syncthreads();
      { f16* tmp = hp; hp = hq; hq = tmp; }
    }
  }

  // =============== DECODER: 32 x (GRU + fc1 + fc2) ===============
  const float dbr = dbih[colm]       + dbhh[colm];
  const float dbz = dbih[256 + colm] + dbhh[256 + colm];
  const float dbn = dbih[512 + colm];
  const float dbh = dbhh[512 + colm];
  const float f1bb = f1b[colm];
  const float f2bb = (c32 < 2) ? f2b[c32] : 0.0f;

  // one-time: FC2 frags -> wfx (wave w loads frags w, w+8); plus s=0 GRU ks0,ks1
  gld16(wfc2L + (size_t)w*512,       wfx + (size_t)w*512);
  gld16(wfc2L + (size_t)(w + 8)*512, wfx + (size_t)(w + 8)*512);
  #pragma unroll
  for (int st = 0; st < 4; ++st) gld16(wdecL + (size_t)(st*16 + 0)*512, sb0 + st*512);
  #pragma unroll
  for (int st = 0; st < 4; ++st) gld16(wdecL + (size_t)(st*16 + 1)*512, sb1 + st*512);
  __syncthreads();   // drains vmcnt -> wfx + ks0,ks1 resident

  #pragma unroll 1
  for (int s = 0; s < 32; ++s){
    // ---- GRU: reads hp, writes h_new -> hq ----
    {
      f32x16 aR[2], aZ[2], aN[2], aH[2];
      #pragma unroll
      for (int rt = 0; rt < 2; ++rt){ aR[rt] = 0.f; aZ[rt] = 0.f; aN[rt] = 0.f; aH[rt] = 0.f; }

      #pragma unroll
      for (int ks = 0; ks < 16; ++ks){
        f16* sb = (ks & 1) ? sb1 : sb0;
        f16x8 b0 = *(const f16x8*)(sb + 0*512 + l*8);
        f16x8 b1 = *(const f16x8*)(sb + 1*512 + l*8);
        f16x8 b2 = *(const f16x8*)(sb + 2*512 + l*8);
        f16x8 b3 = *(const f16x8*)(sb + 3*512 + l*8);
        f16x8 a0 = *(const f16x8*)(hp + ((abase       ) ^ (ks*16)));
        f16x8 a1 = *(const f16x8*)(hp + ((abase + 8192) ^ (ks*16)));
        aR[0] = MFMA32(a0, b0, aR[0]);  aR[1] = MFMA32(a1, b0, aR[1]);
        aZ[0] = MFMA32(a0, b1, aZ[0]);  aZ[1] = MFMA32(a1, b1, aZ[1]);
        aN[0] = MFMA32(a0, b2, aN[0]);  aN[1] = MFMA32(a1, b2, aN[1]);
        aH[0] = MFMA32(a0, b3, aH[0]);  aH[1] = MFMA32(a1, b3, aH[1]);
        if (ks < 14){
          LGKM0();
          #pragma unroll
          for (int st = 0; st < 4; ++st)
            gld16(wdecL + (size_t)(st*16 + ks + 2)*512, sb + st*512);
          VMW(4);
        } else if (ks == 14){ VMW(0); }
      }
      #pragma unroll
      for (int rt = 0; rt < 2; ++rt){
        #pragma unroll
        for (int rg = 0; rg < 16; ++rg){
          int rr  = (rg & 3) + 8*(rg >> 2) + 4*half;
          int row = rt*32 + rr;
          int el  = row*256 + (colm ^ ((rr & 7) << 3));
          float rv = sigm(aR[rt][rg] + dbr);
          float zv = sigm(aZ[rt][rg] + dbz);
          float nv = tanh_f(aN[rt][rg] + dbn + rv*(aH[rt][rg] + dbh));
          float ho = (float)hp[el];
          hq[el] = (f16)(nv + zv*(ho - nv));
        }
      }
    }
    // stage FC1 chunks 0,1 (barrier + epilogue tail cover latency)
    LGKM0();
    #pragma unroll
    for (int p = 0; p < 4; ++p) gld16(wfc1L + (size_t)(0*4 + p)*512, sb0 + p*512);
    #pragma unroll
    for (int p = 0; p < 4; ++p) gld16(wfc1L + (size_t)(1*4 + p)*512, sb1 + p*512);
    __syncthreads();

    // ---- FC1: relu(h_new @ W1.T + b1): reads hq, writes -> hp (h_old dead) ----
    {
      f32x16 aF[2];
      aF[0] = 0.f; aF[1] = 0.f;
      #pragma unroll
      for (int c = 0; c < 4; ++c){
        f16* sb = (c & 1) ? sb1 : sb0;
        f16x8 bb[4];
        #pragma unroll
        for (int p = 0; p < 4; ++p) bb[p] = *(const f16x8*)(sb + p*512 + l*8);
        #pragma unroll
        for (int ksl = 0; ksl < 4; ++ksl){
          int ks = c*4 + ksl;
          f16x8 a0 = *(const f16x8*)(hq + ((abase       ) ^ (ks*16)));
          f16x8 a1 = *(const f16x8*)(hq + ((abase + 8192) ^ (ks*16)));
          aF[0] = MFMA32(a0, bb[ksl], aF[0]);
          aF[1] = MFMA32(a1, bb[ksl], aF[1]);
        }
        if (c < 2){
          LGKM0();
          #pragma unroll
          for (int p = 0; p < 4; ++p)
            gld16(wfc1L + (size_t)((c + 2)*4 + p)*512, sb + p*512);
          VMW(4);
        } else if (c == 2){ VMW(0); }
      }
      #pragma unroll
      for (int rt = 0; rt < 2; ++rt){
        #pragma unroll
        for (int rg = 0; rg < 16; ++rg){
          int rr  = (rg & 3) + 8*(rg >> 2) + 4*half;
          int row = rt*32 + rr;
          int el  = row*256 + (colm ^ ((rr & 7) << 3));
          hp[el] = (f16)fmaxf(aF[rt][rg] + f1bb, 0.0f);
        }
      }
    }
    __syncthreads();

    // ---- FC2 (waves 0-1, B from persistent wfx) + stage next GRU ks0,ks1 ----
    if (s < 31){
      #pragma unroll
      for (int st = 0; st < 4; ++st) gld16(wdecL + (size_t)(st*16 + 0)*512, sb0 + st*512);
      #pragma unroll
      for (int st = 0; st < 4; ++st) gld16(wdecL + (size_t)(st*16 + 1)*512, sb1 + st*512);
    }
    if (w < 2){
      f32x16 a2 = 0.f;
      #pragma unroll
      for (int ks = 0; ks < 16; ++ks){
        f16x8 bv = *(const f16x8*)(wfx + (size_t)ks*512 + l*8);
        f16x8 a0 = *(const f16x8*)(hp + ((abase + w*8192) ^ (ks*16)));
        a2 = MFMA32(a0, bv, a2);
      }
      if (c32 < 2){
        #pragma unroll
        for (int rg = 0; rg < 16; ++rg){
          int row = w*32 + (rg & 3) + 8*(rg >> 2) + 4*half;
          out[((size_t)(r0 + row)*32 + s)*2 + c32] = tanh_f(a2[rg] + f2bb);
        }
      }
    }
    __syncthreads();   // protects hp (FC2 src) from next GRU's writes; drains DMA
    { f16* tmp = hp; hp = hq; hq = tmp; }
  }
}

extern "C" void kernel_launch(void* const* d_in, const int* in_sizes, int n_in,
                              void* d_out, int out_size, void* d_ws, size_t ws_size,
                              hipStream_t stream)
{
  (void)in_sizes; (void)n_in; (void)out_size; (void)ws_size;
  const float* x    = (const float*)d_in[0];
  const float* emW  = (const float*)d_in[1];
  const float* emb_ = (const float*)d_in[2];
  const float* evW  = (const float*)d_in[3];
  const float* evb  = (const float*)d_in[4];
  const float* eWih = (const float*)d_in[5];
  const float* eWhh = (const float*)d_in[6];
  const float* ebih = (const float*)d_in[7];
  const float* ebhh = (const float*)d_in[8];
  const float* dWih = (const float*)d_in[9];
  const float* dWhh = (const float*)d_in[10];
  const float* dbih = (const float*)d_in[11];
  const float* dbhh = (const float*)d_in[12];
  const float* f1W  = (const float*)d_in[13];
  const float* f1b  = (const float*)d_in[14];
  const float* f2W  = (const float*)d_in[15];
  const float* f2b  = (const float*)d_in[16];
  float* out = (float*)d_out;
  f16* ws16 = (f16*)d_ws;

  prep_pack<<<(TOT_E + 255)/256, 256, 0, stream>>>(eWih, eWhh, dWih, dWhh, f1W, f2W, ws16);
  fused_net<<<NBLK, NTHR, 0, stream>>>(x, emW, emb_, evW, evb, ebih, ebhh,
                                       dbih, dbhh, f1b, f2b, ws16, out);
}

// Round 9
// 1311.354 us; speedup vs baseline: 1.1028x; 1.1028x over previous
//
#include <hip/hip_runtime.h>
#include <math.h>
#include <stdint.h>

typedef _Float16 f16;
typedef _Float16 f16x8 __attribute__((ext_vector_type(8)));
typedef float    f32x16 __attribute__((ext_vector_type(16)));

#define NBLK 256
#define NTHR 512
#define MROW 64

// ---- d_ws fragment layout (identical to r6-r8, validated) ----
#define FC1_F 512
#define FC2_F 640
#define ENC_F 656
#define TOT_F 1232
#define TOT_E (TOT_F*512)

#define MFMA32(a,b,c) __builtin_amdgcn_mfma_f32_32x32x16_f16((a),(b),(c),0,0,0)
#define VMW(n)  asm volatile("s_waitcnt vmcnt(" #n ")" ::: "memory")
#define LGKM0() asm volatile("s_waitcnt lgkmcnt(0)" ::: "memory")
#define BARR()  do { __builtin_amdgcn_s_barrier(); asm volatile("" ::: "memory"); } while(0)

__device__ __forceinline__ void gld16(const f16* g, f16* lds){
  __builtin_amdgcn_global_load_lds(
      (const __attribute__((address_space(1))) void*)(uintptr_t)(const void*)g,
      (__attribute__((address_space(3))) void*)(uint32_t)(uintptr_t)(void*)lds,
      16, 0, 0);
}

__device__ __forceinline__ float sigm(float v){
  return __fdividef(1.0f, 1.0f + __expf(-v));
}
__device__ __forceinline__ float tanh_f(float v){
  float t = fminf(v, 8.0f);
  float e = __expf(2.0f * t);
  return 1.0f - 2.0f * __fdividef(1.0f, e + 1.0f);
}
__device__ __forceinline__ int eX(int row, int k){ return row*128 + (k ^ ((row & 7) << 3)); }

// ---------------- prep: pack weights as fp16 32x32x16 B-fragments (byte-identical r6-r8) ----------------
__global__ void prep_pack(const float* __restrict__ eWih, const float* __restrict__ eWhh,
                          const float* __restrict__ dWih, const float* __restrict__ dWhh,
                          const float* __restrict__ f1W,  const float* __restrict__ f2W,
                          f16* __restrict__ ws16)
{
  int idx = blockIdx.x * 256 + threadIdx.x;
  if (idx >= TOT_E) return;
  int frag = idx >> 9;
  int lo   = idx & 511;
  int l    = lo >> 3;
  int jj   = lo & 7;
  int c32  = l & 31;
  int half = l >> 5;
  int kin  = half*8 + jj;
  float v = 0.0f;
  if (frag < FC1_F){
    int ct = frag >> 6, st = (frag >> 4) & 3, ks = frag & 15;
    int col = ct*32 + c32, k = ks*16 + kin;
    if      (st == 0) v = dWih[col*256 + k]        + dWhh[col*256 + k];
    else if (st == 1) v = dWih[(256+col)*256 + k]  + dWhh[(256+col)*256 + k];
    else if (st == 2) v = dWih[(512+col)*256 + k];
    else              v = dWhh[(512+col)*256 + k];
  } else if (frag < FC2_F){
    int f = frag - FC1_F, ct = f >> 4, ks = f & 15;
    int col = ct*32 + c32, k = ks*16 + kin;
    v = f1W[col*256 + k];
  } else if (frag < ENC_F){
    int ks = frag - FC2_F, k = ks*16 + kin;
    v = (c32 < 2) ? f2W[c32*256 + k] : 0.0f;
  } else {
    int f = frag - ENC_F, ct = f / 72, r = f % 72;
    int col = ct*32 + c32;
    if (r < 24){ int st = r >> 3, ks = r & 7;  v = eWih[(st*256 + col)*128 + ks*16 + kin]; }
    else { r -= 24; int st = r >> 4, ks = r & 15; v = eWhh[(st*256 + col)*256 + ks*16 + kin]; }
  }
  ws16[idx] = (f16)v;
}

// ---------------- fused persistent kernel ----------------
__global__ __launch_bounds__(NTHR, 1)
void fused_net(const float* __restrict__ x,
               const float* __restrict__ emW, const float* __restrict__ emb_,
               const float* __restrict__ evW, const float* __restrict__ evb,
               const float* __restrict__ ebih, const float* __restrict__ ebhh,
               const float* __restrict__ dbih, const float* __restrict__ dbhh,
               const float* __restrict__ f1b, const float* __restrict__ f2b,
               const f16* __restrict__ ws16, float* __restrict__ out)
{
  __shared__ __align__(16) f16 hA[16384];   // [64][256] h ping
  __shared__ __align__(16) f16 hB[16384];   // [64][256] h pong / fc1-out
  __shared__ __align__(16) f16 stg[49152];  // dec: 3 slots x 8 waves x 2048
                                            // enc: xb[8192] + 3 slots x 8 waves x 1536

  const int tid  = threadIdx.x;
  const int r0   = blockIdx.x * MROW;
  const int l    = tid & 63;
  const int w    = tid >> 6;
  const int c32  = l & 31;
  const int half = l >> 5;

  f16* hp = hA;
  f16* hq = hB;
  f16* xb = stg;                            // encoder-phase only

  const int abase = c32*256 + ((half*8) ^ ((l & 7) << 3));
  const int xbase = c32*128 + ((half*8) ^ ((l & 7) << 3));
  const int colm  = w*32 + c32;

  f16* d0 = stg + (size_t)(0*8 + w)*2048;   // decoder staging slots (wave-private)
  f16* d1 = stg + (size_t)(1*8 + w)*2048;
  f16* d2 = stg + (size_t)(2*8 + w)*2048;
  f16* e0 = stg + 8192 + (size_t)(0*8 + w)*1536;  // encoder staging slots
  f16* e1 = stg + 8192 + (size_t)(1*8 + w)*1536;
  f16* e2 = stg + 8192 + (size_t)(2*8 + w)*1536;

  const f16* wdecL = ws16 + (size_t)(w*64)*512           + (size_t)l*8;
  const f16* wfc1L = ws16 + (size_t)(FC1_F + w*16)*512   + (size_t)l*8;
  const f16* wfc2L = ws16 + (size_t)FC2_F*512            + (size_t)l*8;
  const f16* wencL = ws16 + (size_t)(ENC_F + w*72)*512   + (size_t)l*8;

  for (int i = tid; i < 16384; i += NTHR) hA[i] = (f16)0.0f;   // h0 = 0
  __syncthreads();

  // =============== ENCODER: 9 GRU steps ===============
  {
    const float ebr = ebih[colm]       + ebhh[colm];
    const float ebz = ebih[256 + colm] + ebhh[256 + colm];
    const float ebn = ebih[512 + colm];
    const float ebh = ebhh[512 + colm];

    #pragma unroll 1
    for (int t = 0; t < 9; ++t){
      // issue batches 0,1 (units 0,1); embed phase covers latency
      #pragma unroll
      for (int st = 0; st < 3; ++st) gld16(wencL + (size_t)(st*8 + 0)*512, e0 + st*512);
      #pragma unroll
      for (int st = 0; st < 3; ++st) gld16(wencL + (size_t)(st*8 + 1)*512, e1 + st*512);

      { // xt = tanh(embedding) -> xb
        int e  = tid & 127;
        int rq = tid >> 7;
        const float* Wp = (t < 8) ? (evW + e*6) : (emW + e*6);
        float bb = (t < 8) ? evb[e] : emb_[e];
        float w0 = Wp[0], w1 = Wp[1], w2 = Wp[2], w3 = Wp[3], w4 = Wp[4], w5 = Wp[5];
        int xo = (t < 8) ? (6 + t*6) : 0;
        #pragma unroll 1
        for (int rr = 0; rr < 16; ++rr){
          int row = rq*16 + rr;
          const float* xs = x + (size_t)(r0 + row)*54 + xo;
          float a = bb + xs[0]*w0 + xs[1]*w1 + xs[2]*w2 + xs[3]*w3 + xs[4]*w4 + xs[5]*w5;
          xb[eX(row, e)] = (f16)tanh_f(a);
        }
      }
      LGKM0(); BARR();

      f32x16 aR[2], aZ[2], aN[2], aH[2];
      #pragma unroll
      for (int rt = 0; rt < 2; ++rt){ aR[rt] = 0.f; aZ[rt] = 0.f; aN[rt] = 0.f; aH[rt] = 0.f; }

      f16* s0 = e0; f16* s1 = e1; f16* s2 = e2;
      #pragma unroll 1
      for (int u = 0; u < 24; ++u){
        if (u < 23) { VMW(3); } else { VMW(0); }
        f16x8 b0 = *(const f16x8*)(s0 + 0*512 + l*8);
        f16x8 b1 = *(const f16x8*)(s0 + 1*512 + l*8);
        f16x8 b2 = *(const f16x8*)(s0 + 2*512 + l*8);
        if (u < 22){                                // issue batch u+2 into s2
          int uu = u + 2;
          int Fbase = (uu < 8) ? uu : (24 + (uu - 8));
          int Fstep = (uu < 8) ? 8 : 16;
          const f16* g = wencL + (size_t)Fbase*512;
          #pragma unroll
          for (int st = 0; st < 3; ++st) gld16(g + (size_t)st*Fstep*512, s2 + st*512);
        }
        if (u < 8){
          int ao = xbase ^ (u << 4);
          f16x8 a0 = *(const f16x8*)(xb + ao);
          f16x8 a1 = *(const f16x8*)(xb + ao + 4096);
          aR[0] = MFMA32(a0, b0, aR[0]);  aR[1] = MFMA32(a1, b0, aR[1]);
          aZ[0] = MFMA32(a0, b1, aZ[0]);  aZ[1] = MFMA32(a1, b1, aZ[1]);
          aN[0] = MFMA32(a0, b2, aN[0]);  aN[1] = MFMA32(a1, b2, aN[1]);
        } else {
          int ao = abase ^ ((u - 8) << 4);
          f16x8 a0 = *(const f16x8*)(hp + ao);
          f16x8 a1 = *(const f16x8*)(hp + ao + 8192);
          aR[0] = MFMA32(a0, b0, aR[0]);  aR[1] = MFMA32(a1, b0, aR[1]);
          aZ[0] = MFMA32(a0, b1, aZ[0]);  aZ[1] = MFMA32(a1, b1, aZ[1]);
          aH[0] = MFMA32(a0, b2, aH[0]);  aH[1] = MFMA32(a1, b2, aH[1]);
        }
        f16* tt = s0; s0 = s1; s1 = s2; s2 = tt;
      }
      // epilogue -> hq
      #pragma unroll
      for (int rt = 0; rt < 2; ++rt){
        #pragma unroll
        for (int rg = 0; rg < 16; ++rg){
          int rr  = (rg & 3) + 8*(rg >> 2) + 4*half;
          int row = rt*32 + rr;
          int el  = row*256 + (colm ^ ((rr & 7) << 3));
          float rv = sigm(aR[rt][rg] + ebr);
          float zv = sigm(aZ[rt][rg] + ebz);
          float nv = tanh_f(aN[rt][rg] + ebn + rv*(aH[rt][rg] + ebh));
          float ho = (float)hp[el];
          hq[el] = (f16)(nv + zv*(ho - nv));
        }
      }
      LGKM0(); BARR();
      { f16* tmp = hp; hp = hq; hq = tmp; }
    }
  }

  // =============== DECODER: 32 x (GRU + fc1 + fc2) ===============
  const float dbr = dbih[colm]       + dbhh[colm];
  const float dbz = dbih[256 + colm] + dbhh[256 + colm];
  const float dbn = dbih[512 + colm];
  const float dbh = dbhh[512 + colm];
  const float f1bb = f1b[colm];
  const float f2bb = (c32 < 2) ? f2b[c32] : 0.0f;

  // FC1 weights persistent in registers (64 VGPR/lane, loaded once)
  f16x8 bf[16];
  #pragma unroll
  for (int p = 0; p < 16; ++p) bf[p] = *(const f16x8*)(wfc1L + (size_t)p*512);

  // prologue: GRU batches 0,1
  #pragma unroll
  for (int st = 0; st < 4; ++st) gld16(wdecL + (size_t)(st*16 + 0)*512, d0 + st*512);
  #pragma unroll
  for (int st = 0; st < 4; ++st) gld16(wdecL + (size_t)(st*16 + 1)*512, d1 + st*512);

  #pragma unroll 1
  for (int s = 0; s < 32; ++s){
    // ---- GRU: reads hp, writes h_new -> hq ----
    {
      f32x16 aR[2], aZ[2], aN[2], aH[2];
      #pragma unroll
      for (int rt = 0; rt < 2; ++rt){ aR[rt] = 0.f; aZ[rt] = 0.f; aN[rt] = 0.f; aH[rt] = 0.f; }

      f16* s0 = d0; f16* s1 = d1; f16* s2 = d2;
      #pragma unroll 1
      for (int u = 0; u < 16; ++u){
        if (u < 15) { VMW(4); } else { VMW(0); }
        f16x8 b0 = *(const f16x8*)(s0 + 0*512 + l*8);
        f16x8 b1 = *(const f16x8*)(s0 + 1*512 + l*8);
        f16x8 b2 = *(const f16x8*)(s0 + 2*512 + l*8);
        f16x8 b3 = *(const f16x8*)(s0 + 3*512 + l*8);
        if (u < 14){                                // issue batch u+2 into s2
          const f16* g = wdecL + (size_t)(u + 2)*512;
          #pragma unroll
          for (int st = 0; st < 4; ++st) gld16(g + (size_t)st*16*512, s2 + st*512);
        }
        int ao = abase ^ (u << 4);
        f16x8 a0 = *(const f16x8*)(hp + ao);
        f16x8 a1 = *(const f16x8*)(hp + ao + 8192);
        aR[0] = MFMA32(a0, b0, aR[0]);  aR[1] = MFMA32(a1, b0, aR[1]);
        aZ[0] = MFMA32(a0, b1, aZ[0]);  aZ[1] = MFMA32(a1, b1, aZ[1]);
        aN[0] = MFMA32(a0, b2, aN[0]);  aN[1] = MFMA32(a1, b2, aN[1]);
        aH[0] = MFMA32(a0, b3, aH[0]);  aH[1] = MFMA32(a1, b3, aH[1]);
        f16* tt = s0; s0 = s1; s1 = s2; s2 = tt;
      }
      // issue NEXT step's batches 0,1 (epilogue + FC1 + FC2 cover the latency)
      if (s < 31){
        #pragma unroll
        for (int st = 0; st < 4; ++st) gld16(wdecL + (size_t)(st*16 + 0)*512, d0 + st*512);
        #pragma unroll
        for (int st = 0; st < 4; ++st) gld16(wdecL + (size_t)(st*16 + 1)*512, d1 + st*512);
      }
      #pragma unroll
      for (int rt = 0; rt < 2; ++rt){
        #pragma unroll
        for (int rg = 0; rg < 16; ++rg){
          int rr  = (rg & 3) + 8*(rg >> 2) + 4*half;
          int row = rt*32 + rr;
          int el  = row*256 + (colm ^ ((rr & 7) << 3));
          float rv = sigm(aR[rt][rg] + dbr);
          float zv = sigm(aZ[rt][rg] + dbz);
          float nv = tanh_f(aN[rt][rg] + dbn + rv*(aH[rt][rg] + dbh));
          float ho = (float)hp[el];
          hq[el] = (f16)(nv + zv*(ho - nv));
        }
      }
    }
    LGKM0(); BARR();

    // ---- FC1: relu(h_new @ W1.T + b1): reads hq, B from persistent regs, writes -> hp ----
    {
      f32x16 aF0 = 0.f, aF1 = 0.f;
      #pragma unroll
      for (int ks = 0; ks < 16; ++ks){
        int ao = abase ^ (ks << 4);
        f16x8 a0 = *(const f16x8*)(hq + ao);
        f16x8 a1 = *(const f16x8*)(hq + ao + 8192);
        aF0 = MFMA32(a0, bf[ks], aF0);
        aF1 = MFMA32(a1, bf[ks], aF1);
      }
      #pragma unroll
      for (int rg = 0; rg < 16; ++rg){
        int rr  = (rg & 3) + 8*(rg >> 2) + 4*half;
        int el0 = rr*256        + (colm ^ ((rr & 7) << 3));
        int el1 = (32 + rr)*256 + (colm ^ ((rr & 7) << 3));
        hp[el0] = (f16)fmaxf(aF0[rg] + f1bb, 0.0f);
        hp[el1] = (f16)fmaxf(aF1[rg] + f1bb, 0.0f);
      }
    }
    LGKM0(); BARR();

    // ---- FC2 (waves 0-1, B direct global->reg): y = tanh(act @ W2.T + b2) -> out ----
    if (w < 2){
      f32x16 a2 = 0.f;
      #pragma unroll
      for (int ks = 0; ks < 16; ++ks){
        f16x8 bv = *(const f16x8*)(wfc2L + (size_t)ks*512);
        f16x8 a0 = *(const f16x8*)(hp + ((abase + w*8192) ^ (ks << 4)));
        a2 = MFMA32(a0, bv, a2);
      }
      if (c32 < 2){
        #pragma unroll
        for (int rg = 0; rg < 16; ++rg){
          int row = w*32 + (rg & 3) + 8*(rg >> 2) + 4*half;
          out[((size_t)(r0 + row)*32 + s)*2 + c32] = tanh_f(a2[rg] + f2bb);
        }
      }
    }
    LGKM0(); BARR();   // protects hp (FC2 src) from next GRU's hq-buffer writes after swap
    { f16* tmp = hp; hp = hq; hq = tmp; }
  }
}

extern "C" void kernel_launch(void* const* d_in, const int* in_sizes, int n_in,
                              void* d_out, int out_size, void* d_ws, size_t ws_size,
                              hipStream_t stream)
{
  (void)in_sizes; (void)n_in; (void)out_size; (void)ws_size;
  const float* x    = (const float*)d_in[0];
  const float* emW  = (const float*)d_in[1];
  const float* emb_ = (const float*)d_in[2];
  const float* evW  = (const float*)d_in[3];
  const float* evb  = (const float*)d_in[4];
  const float* eWih = (const float*)d_in[5];
  const float* eWhh = (const float*)d_in[6];
  const float* ebih = (const float*)d_in[7];
  const float* ebhh = (const float*)d_in[8];
  const float* dWih = (const float*)d_in[9];
  const float* dWhh = (const float*)d_in[10];
  const float* dbih = (const float*)d_in[11];
  const float* dbhh = (const float*)d_in[12];
  const float* f1W  = (const float*)d_in[13];
  const float* f1b  = (const float*)d_in[14];
  const float* f2W  = (const float*)d_in[15];
  const float* f2b  = (const float*)d_in[16];
  float* out = (float*)d_out;
  f16* ws16 = (f16*)d_ws;

  prep_pack<<<(TOT_E + 255)/256, 256, 0, stream>>>(eWih, eWhh, dWih, dWhh, f1W, f2W, ws16);
  fused_net<<<NBLK, NTHR, 0, stream>>>(x, emW, emb_, evW, evb, ebih, ebhh,
                                       dbih, dbhh, f1b, f2b, ws16, out);
}